// Round 1
// baseline (535.021 us; speedup 1.0000x reference)
//
#include <hip/hip_runtime.h>
#include <cmath>

#define BATCH 32
#define NA 8400
#define NC 80
#define MAXDET 100
#define NMSTHR 0.65f
#define SCTHR 0.01f
#define NEG_INF (-INFINITY)

#define NT 512          // NMS threads per block
#define CH 17           // ceil(8400/512)

__device__ __forceinline__ float stable_sigmoid(float x) {
    if (x >= 0.f) return 1.f / (1.f + expf(-x));
    float e = expf(x);
    return e / (1.f + e);
}

// One thread per (image, anchor): max/argmax over 80 classes, sigmoid scores,
// box decode. Writes boxes (float4), scores, labels to workspace.
__global__ __launch_bounds__(256) void decode_kernel(
    const float* __restrict__ cls0, const float* __restrict__ reg0, const float* __restrict__ obj0,
    const float* __restrict__ cls1, const float* __restrict__ reg1, const float* __restrict__ obj1,
    const float* __restrict__ cls2, const float* __restrict__ reg2, const float* __restrict__ obj2,
    float4* __restrict__ wboxes, float* __restrict__ wscores, int* __restrict__ wlabels)
{
    int gid = blockIdx.x * blockDim.x + threadIdx.x;
    if (gid >= BATCH * NA) return;
    int b = gid / NA;
    int j = gid - b * NA;

    const float *cls, *reg, *obj;
    int hw, w_, p;
    float s;
    if (j < 6400)      { cls = cls0; reg = reg0; obj = obj0; hw = 6400; w_ = 80; s = 8.f;  p = j; }
    else if (j < 8000) { cls = cls1; reg = reg1; obj = obj1; hw = 1600; w_ = 40; s = 16.f; p = j - 6400; }
    else               { cls = cls2; reg = reg2; obj = obj2; hw = 400;  w_ = 20; s = 32.f; p = j - 8000; }

    int y = p / w_;
    int x = p - y * w_;

    // class max / argmax (first occurrence of max, matching jnp.argmax)
    const float* cbase = cls + (size_t)b * NC * hw + p;
    float maxv = NEG_INF;
    int lab = 0;
    for (int c = 0; c < NC; ++c) {
        float v = cbase[(size_t)c * hw];
        if (v > maxv) { maxv = v; lab = c; }
    }

    float objv = obj[(size_t)b * hw + p];
    float score = stable_sigmoid(maxv) * stable_sigmoid(objv);

    const float* rbase = reg + (size_t)b * 4 * hw + p;
    float r0 = rbase[0];
    float r1 = rbase[hw];
    float r2 = rbase[2 * (size_t)hw];
    float r3 = rbase[3 * (size_t)hw];

    float cx = r0 * s + (float)x * s;
    float cy = r1 * s + (float)y * s;
    float bw = expf(r2) * s;
    float bh = expf(r3) * s;

    float4 box = make_float4(cx - bw * 0.5f, cy - bh * 0.5f,
                             cx + bw * 0.5f, cy + bh * 0.5f);
    wboxes[gid] = box;
    wscores[gid] = score;
    wlabels[gid] = lab;
}

// One block per image. Exact replication of the reference's 100-iteration
// greedy NMS on class-offset boxes (offset = max|coords|+1 — note this does
// NOT make classes fully disjoint for negative coords, so we keep the exact
// sequential semantics instead of per-class decomposition).
__global__ __launch_bounds__(NT) void nms_kernel(
    const float4* __restrict__ wboxes, const float* __restrict__ wscores,
    const int* __restrict__ wlabels, float* __restrict__ out)
{
    int b = blockIdx.x;
    int t = threadIdx.x;
    const float4* boxes  = wboxes  + (size_t)b * NA;
    const float*  scores = wscores + (size_t)b * NA;
    const int*    labels = wlabels + (size_t)b * NA;

    __shared__ float s_red_s[NT / 64];
    __shared__ int   s_red_j[NT / 64];
    __shared__ float s_bbox[4];
    __shared__ int   s_bj;
    __shared__ float s_off;
    __shared__ int   s_keep[MAXDET];
    __shared__ float s_ksc[MAXDET];

    float4 bx[CH];
    float  lv[CH];

    // pass 1: load boxes, per-image max |coord|
    float m = 0.f;
    #pragma unroll
    for (int k = 0; k < CH; ++k) {
        int j = t + k * NT;
        if (j < NA) {
            float4 v = boxes[j];
            bx[k] = v;
            m = fmaxf(m, fmaxf(fmaxf(fabsf(v.x), fabsf(v.y)),
                               fmaxf(fabsf(v.z), fabsf(v.w))));
        } else {
            bx[k] = make_float4(0.f, 0.f, 0.f, 0.f);
        }
    }
    #pragma unroll
    for (int o = 32; o >= 1; o >>= 1) m = fmaxf(m, __shfl_xor(m, o));
    if ((t & 63) == 0) s_red_s[t >> 6] = m;
    __syncthreads();
    if (t == 0) {
        float mm = 0.f;
        for (int wv = 0; wv < NT / 64; ++wv) mm = fmaxf(mm, s_red_s[wv]);
        s_off = mm + 1.f;
    }
    __syncthreads();
    float offset = s_off;

    // pass 2: apply class offsets, init live scores
    #pragma unroll
    for (int k = 0; k < CH; ++k) {
        int j = t + k * NT;
        if (j < NA) {
            float lo = (float)labels[j] * offset;
            bx[k].x += lo; bx[k].y += lo; bx[k].z += lo; bx[k].w += lo;
            float sc = scores[j];
            lv[k] = (sc >= SCTHR) ? sc : NEG_INF;
        } else {
            lv[k] = NEG_INF;
        }
    }

    for (int it = 0; it < MAXDET; ++it) {
        // local argmax (higher score wins; tie -> lower index, matching jnp.argmax)
        float ls = NEG_INF;
        int   lj = 0x7fffffff;
        #pragma unroll
        for (int k = 0; k < CH; ++k) {
            int j = t + k * NT;
            if (lv[k] > ls || (lv[k] == ls && j < lj)) { ls = lv[k]; lj = j; }
        }
        // wave reduce (64 lanes)
        #pragma unroll
        for (int o = 32; o >= 1; o >>= 1) {
            float os = __shfl_xor(ls, o);
            int   oj = __shfl_xor(lj, o);
            if (os > ls || (os == ls && oj < lj)) { ls = os; lj = oj; }
        }
        if ((t & 63) == 0) { s_red_s[t >> 6] = ls; s_red_j[t >> 6] = lj; }
        __syncthreads();
        if (t == 0) {
            float bs = NEG_INF;
            int   bj = 0x7fffffff;
            for (int wv = 0; wv < NT / 64; ++wv) {
                float os = s_red_s[wv];
                int   oj = s_red_j[wv];
                if (os > bs || (os == bs && oj < bj)) { bs = os; bj = oj; }
            }
            s_keep[it] = bj;
            s_ksc[it]  = bs;   // live[best] at pick time (== original score or -inf)
            s_bj = bj;
        }
        __syncthreads();
        int bj = s_bj;
        // owner broadcasts the best (offset) box
        #pragma unroll
        for (int k = 0; k < CH; ++k) {
            int j = t + k * NT;
            if (j == bj) {
                s_bbox[0] = bx[k].x; s_bbox[1] = bx[k].y;
                s_bbox[2] = bx[k].z; s_bbox[3] = bx[k].w;
            }
        }
        __syncthreads();
        float b0 = s_bbox[0], b1 = s_bbox[1], b2 = s_bbox[2], b3 = s_bbox[3];
        float a1 = (b2 - b0) * (b3 - b1);
        #pragma unroll
        for (int k = 0; k < CH; ++k) {
            int j = t + k * NT;
            if (j == bj) {
                lv[k] = NEG_INF;
            } else {
                float tlx = fmaxf(b0, bx[k].x);
                float tly = fmaxf(b1, bx[k].y);
                float brx = fminf(b2, bx[k].z);
                float bry = fminf(b3, bx[k].w);
                float ww = fmaxf(brx - tlx, 0.f);
                float hh = fmaxf(bry - tly, 0.f);
                float inter = ww * hh;
                float a2 = (bx[k].z - bx[k].x) * (bx[k].w - bx[k].y);
                float iou = inter / (a1 + a2 - inter + 1e-6f);
                if (iou > NMSTHR) lv[k] = NEG_INF;
            }
        }
    }
    __syncthreads();

    // epilogue: write boxes/scores/labels/valid (all fp32; labels/valid as floats)
    if (t < MAXDET) {
        float ks = s_ksc[t];
        int   kj = s_keep[t];
        bool valid = ks > NEG_INF;
        float4 obx = make_float4(0.f, 0.f, 0.f, 0.f);
        float osc = 0.f, olab = -1.f, oval = 0.f;
        if (valid) {
            obx  = boxes[kj];          // raw (non-offset) box
            osc  = ks;
            olab = (float)labels[kj];
            oval = 1.f;
        }
        float* ob = out + ((size_t)b * MAXDET + t) * 4;
        ob[0] = obx.x; ob[1] = obx.y; ob[2] = obx.z; ob[3] = obx.w;
        out[BATCH * MAXDET * 4 + b * MAXDET + t] = osc;
        out[BATCH * MAXDET * 5 + b * MAXDET + t] = olab;
        out[BATCH * MAXDET * 6 + b * MAXDET + t] = oval;
    }
}

extern "C" void kernel_launch(void* const* d_in, const int* in_sizes, int n_in,
                              void* d_out, int out_size, void* d_ws, size_t ws_size,
                              hipStream_t stream) {
    // setup_inputs() dict order: cls0, reg0, obj0, cls1, reg1, obj1, cls2, reg2, obj2
    const float* cls0 = (const float*)d_in[0];
    const float* reg0 = (const float*)d_in[1];
    const float* obj0 = (const float*)d_in[2];
    const float* cls1 = (const float*)d_in[3];
    const float* reg1 = (const float*)d_in[4];
    const float* obj1 = (const float*)d_in[5];
    const float* cls2 = (const float*)d_in[6];
    const float* reg2 = (const float*)d_in[7];
    const float* obj2 = (const float*)d_in[8];

    // workspace layout: boxes float4[B*NA] | scores float[B*NA] | labels int[B*NA]
    char* ws = (char*)d_ws;
    float4* wboxes  = (float4*)ws;
    float*  wscores = (float*)(ws + (size_t)BATCH * NA * sizeof(float4));
    int*    wlabels = (int*)(ws + (size_t)BATCH * NA * (sizeof(float4) + sizeof(float)));

    int total = BATCH * NA;  // 268800 = 1050 * 256
    decode_kernel<<<(total + 255) / 256, 256, 0, stream>>>(
        cls0, reg0, obj0, cls1, reg1, obj1, cls2, reg2, obj2,
        wboxes, wscores, wlabels);

    nms_kernel<<<BATCH, NT, 0, stream>>>(wboxes, wscores, wlabels, (float*)d_out);
}

// Round 2
// 493.925 us; speedup vs baseline: 1.0832x; 1.0832x over previous
//
#include <hip/hip_runtime.h>
#include <cmath>

#define BATCH 32
#define NA 8400
#define NC 80
#define MAXDET 100
#define NMSTHR 0.65f
#define SCTHR 0.01f
#define NEG_INF (-INFINITY)

#define NT 512          // NMS threads per block
#define CH 17           // ceil(8400/512)
#define NW (NT / 64)    // waves per block

__device__ __forceinline__ float stable_sigmoid(float x) {
    if (x >= 0.f) return 1.f / (1.f + expf(-x));
    float e = expf(x);
    return e / (1.f + e);
}

// One thread per 4 consecutive anchors (float4 loads). Level sizes
// (6400/1600/400) are divisible by 4, so a float4 never crosses a level.
__global__ __launch_bounds__(256) void decode_kernel(
    const float* __restrict__ cls0, const float* __restrict__ reg0, const float* __restrict__ obj0,
    const float* __restrict__ cls1, const float* __restrict__ reg1, const float* __restrict__ obj1,
    const float* __restrict__ cls2, const float* __restrict__ reg2, const float* __restrict__ obj2,
    float4* __restrict__ wboxes, float* __restrict__ wscores, int* __restrict__ wlabels)
{
    int a = blockIdx.x * blockDim.x + threadIdx.x;
    if (a >= BATCH * (NA / 4)) return;
    int b = a / (NA / 4);
    int j = (a - b * (NA / 4)) * 4;   // base anchor, multiple of 4

    const float *cls, *reg, *obj;
    int hw, w_, p;
    float s;
    if (j < 6400)      { cls = cls0; reg = reg0; obj = obj0; hw = 6400; w_ = 80; s = 8.f;  p = j; }
    else if (j < 8000) { cls = cls1; reg = reg1; obj = obj1; hw = 1600; w_ = 40; s = 16.f; p = j - 6400; }
    else               { cls = cls2; reg = reg2; obj = obj2; hw = 400;  w_ = 20; s = 32.f; p = j - 8000; }

    // class max/argmax over 80 channels, 4 anchors at once (first-max wins,
    // matching jnp.argmax)
    const float4* cbase = (const float4*)(cls + (size_t)b * NC * hw + p);
    int hw4 = hw >> 2;
    float maxv[4] = {NEG_INF, NEG_INF, NEG_INF, NEG_INF};
    int   lab[4]  = {0, 0, 0, 0};
    #pragma unroll 4
    for (int c = 0; c < NC; ++c) {
        float4 v = cbase[(size_t)c * hw4];
        if (v.x > maxv[0]) { maxv[0] = v.x; lab[0] = c; }
        if (v.y > maxv[1]) { maxv[1] = v.y; lab[1] = c; }
        if (v.z > maxv[2]) { maxv[2] = v.z; lab[2] = c; }
        if (v.w > maxv[3]) { maxv[3] = v.w; lab[3] = c; }
    }

    const float* rb = reg + (size_t)b * 4 * hw + p;
    float4 r0 = *(const float4*)(rb);
    float4 r1 = *(const float4*)(rb + hw);
    float4 r2 = *(const float4*)(rb + 2 * (size_t)hw);
    float4 r3 = *(const float4*)(rb + 3 * (size_t)hw);
    float4 ov = *(const float4*)(obj + (size_t)b * hw + p);

    float rx[4] = {r0.x, r0.y, r0.z, r0.w};
    float ry[4] = {r1.x, r1.y, r1.z, r1.w};
    float rw[4] = {r2.x, r2.y, r2.z, r2.w};
    float rh[4] = {r3.x, r3.y, r3.z, r3.w};
    float ob[4] = {ov.x, ov.y, ov.z, ov.w};

    float sc4[4];
    int   lb4[4];
    size_t gbase = (size_t)b * NA + j;
    #pragma unroll
    for (int e = 0; e < 4; ++e) {
        int pp = p + e;
        int y = pp / w_;
        int x = pp - y * w_;
        float score = stable_sigmoid(maxv[e]) * stable_sigmoid(ob[e]);
        float cx = rx[e] * s + (float)x * s;
        float cy = ry[e] * s + (float)y * s;
        float bw = expf(rw[e]) * s;
        float bh = expf(rh[e]) * s;
        wboxes[gbase + e] = make_float4(cx - bw * 0.5f, cy - bh * 0.5f,
                                        cx + bw * 0.5f, cy + bh * 0.5f);
        sc4[e] = score;
        lb4[e] = lab[e];
    }
    *(float4*)(wscores + gbase) = make_float4(sc4[0], sc4[1], sc4[2], sc4[3]);
    *(int4*)(wlabels + gbase)   = make_int4(lb4[0], lb4[1], lb4[2], lb4[3]);
}

// One block per image; exact sequential-greedy semantics of the reference.
// All boxes/live-scores register-resident (launch_bounds(…,2) -> 256-VGPR cap,
// no scratch spill). ONE barrier per iteration: per-wave leaders publish
// (score, idx, box) to double-buffered LDS candidates; every thread then
// redundantly reduces the 8 candidates.
__global__ __launch_bounds__(NT, 2) void nms_kernel(
    const float4* __restrict__ wboxes, const float* __restrict__ wscores,
    const int* __restrict__ wlabels, float* __restrict__ out)
{
    int b = blockIdx.x;
    int t = threadIdx.x;
    const float4* boxes  = wboxes  + (size_t)b * NA;
    const float*  scores = wscores + (size_t)b * NA;
    const int*    labels = wlabels + (size_t)b * NA;

    __shared__ float s_cs[2][NW];
    __shared__ int   s_cj[2][NW];
    __shared__ float s_cb[2][NW][4];
    __shared__ float s_red[NW];
    __shared__ float s_off;
    __shared__ int   s_keep[MAXDET];
    __shared__ float s_ksc[MAXDET];

    float4 bx[CH];   // class-offset boxes
    float  lv[CH];   // live scores
    float  a2c[CH];  // precomputed areas

    // pass 1: load boxes, per-image max |coord|
    float m = 0.f;
    #pragma unroll
    for (int k = 0; k < CH; ++k) {
        int j = t + k * NT;
        if (j < NA) {
            float4 v = boxes[j];
            bx[k] = v;
            m = fmaxf(m, fmaxf(fmaxf(fabsf(v.x), fabsf(v.y)),
                               fmaxf(fabsf(v.z), fabsf(v.w))));
        } else {
            bx[k] = make_float4(0.f, 0.f, 0.f, 0.f);
        }
    }
    #pragma unroll
    for (int o = 32; o >= 1; o >>= 1) m = fmaxf(m, __shfl_xor(m, o));
    if ((t & 63) == 0) s_red[t >> 6] = m;
    __syncthreads();
    if (t == 0) {
        float mm = 0.f;
        for (int wv = 0; wv < NW; ++wv) mm = fmaxf(mm, s_red[wv]);
        s_off = mm + 1.f;
    }
    __syncthreads();
    float offset = s_off;

    // pass 2: class offsets, live init, areas
    #pragma unroll
    for (int k = 0; k < CH; ++k) {
        int j = t + k * NT;
        if (j < NA) {
            float lo = (float)labels[j] * offset;
            bx[k].x += lo; bx[k].y += lo; bx[k].z += lo; bx[k].w += lo;
            float sc = scores[j];
            lv[k] = (sc >= SCTHR) ? sc : NEG_INF;
        } else {
            lv[k] = NEG_INF;
        }
        a2c[k] = (bx[k].z - bx[k].x) * (bx[k].w - bx[k].y);
    }

    int par = 0;
    for (int it = 0; it < MAXDET; ++it) {
        // local argmax with box ride-along; strict '>' keeps lowest j on ties
        float ls = NEG_INF;
        int   lj = -1;
        float4 lb = bx[0];
        #pragma unroll
        for (int k = 0; k < CH; ++k) {
            int j = t + k * NT;
            if (lv[k] > ls) { ls = lv[k]; lj = j; lb = bx[k]; }
        }
        // wave butterfly on (score, idx); tie -> lower idx
        #pragma unroll
        for (int o = 32; o >= 1; o >>= 1) {
            float os = __shfl_xor(ls, o);
            int   oj = __shfl_xor(lj, o);
            if (os > ls || (os == ls && (unsigned)oj < (unsigned)lj)) { ls = os; lj = oj; }
        }
        // the lane owning the wave-winner writes its local best box + (ls,lj)
        int wv = t >> 6;
        if (t == (lj & (NT - 1)) && lj >= 0) {
            s_cs[par][wv] = ls;
            s_cj[par][wv] = lj;
            s_cb[par][wv][0] = lb.x; s_cb[par][wv][1] = lb.y;
            s_cb[par][wv][2] = lb.z; s_cb[par][wv][3] = lb.w;
        } else if (lj < 0 && (t & 63) == 0) {   // dead wave: publish -inf
            s_cs[par][wv] = NEG_INF;
            s_cj[par][wv] = -1;
        }
        __syncthreads();   // the ONLY barrier per iteration

        // every thread reduces the NW candidates (broadcast LDS reads)
        float bs = NEG_INF;
        int   bj = -1;
        float b0 = 0.f, b1 = 0.f, b2 = 0.f, b3 = 0.f;
        #pragma unroll
        for (int wvr = 0; wvr < NW; ++wvr) {
            float cs = s_cs[par][wvr];
            int   cj = s_cj[par][wvr];
            if (cs > bs || (cs == bs && (unsigned)cj < (unsigned)bj)) {
                bs = cs; bj = cj;
                b0 = s_cb[par][wvr][0]; b1 = s_cb[par][wvr][1];
                b2 = s_cb[par][wvr][2]; b3 = s_cb[par][wvr][3];
            }
        }
        if (t == 0) { s_keep[it] = bj; s_ksc[it] = bs; }

        // suppression (register-local, no sync needed)
        float a1 = (b2 - b0) * (b3 - b1);
        #pragma unroll
        for (int k = 0; k < CH; ++k) {
            int j = t + k * NT;
            if (j == bj) {
                lv[k] = NEG_INF;
            } else {
                float tlx = fmaxf(b0, bx[k].x);
                float tly = fmaxf(b1, bx[k].y);
                float brx = fminf(b2, bx[k].z);
                float bry = fminf(b3, bx[k].w);
                float ww = fmaxf(brx - tlx, 0.f);
                float hh = fmaxf(bry - tly, 0.f);
                float inter = ww * hh;
                float iou = inter / (a1 + a2c[k] - inter + 1e-6f);
                if (iou > NMSTHR) lv[k] = NEG_INF;
            }
        }
        par ^= 1;
    }
    __syncthreads();

    // epilogue: boxes/scores/labels/valid, all fp32
    if (t < MAXDET) {
        float ks = s_ksc[t];
        int   kj = s_keep[t];
        bool valid = (ks > NEG_INF) && (kj >= 0);
        float4 obx = make_float4(0.f, 0.f, 0.f, 0.f);
        float osc = 0.f, olab = -1.f, oval = 0.f;
        if (valid) {
            obx  = boxes[kj];          // raw (non-offset) box
            osc  = ks;
            olab = (float)labels[kj];
            oval = 1.f;
        }
        float* ob = out + ((size_t)b * MAXDET + t) * 4;
        ob[0] = obx.x; ob[1] = obx.y; ob[2] = obx.z; ob[3] = obx.w;
        out[BATCH * MAXDET * 4 + b * MAXDET + t] = osc;
        out[BATCH * MAXDET * 5 + b * MAXDET + t] = olab;
        out[BATCH * MAXDET * 6 + b * MAXDET + t] = oval;
    }
}

extern "C" void kernel_launch(void* const* d_in, const int* in_sizes, int n_in,
                              void* d_out, int out_size, void* d_ws, size_t ws_size,
                              hipStream_t stream) {
    // setup_inputs() dict order: cls0, reg0, obj0, cls1, reg1, obj1, cls2, reg2, obj2
    const float* cls0 = (const float*)d_in[0];
    const float* reg0 = (const float*)d_in[1];
    const float* obj0 = (const float*)d_in[2];
    const float* cls1 = (const float*)d_in[3];
    const float* reg1 = (const float*)d_in[4];
    const float* obj1 = (const float*)d_in[5];
    const float* cls2 = (const float*)d_in[6];
    const float* reg2 = (const float*)d_in[7];
    const float* obj2 = (const float*)d_in[8];

    char* ws = (char*)d_ws;
    float4* wboxes  = (float4*)ws;
    float*  wscores = (float*)(ws + (size_t)BATCH * NA * sizeof(float4));
    int*    wlabels = (int*)(ws + (size_t)BATCH * NA * (sizeof(float4) + sizeof(float)));

    int total4 = BATCH * (NA / 4);   // 67200
    decode_kernel<<<(total4 + 255) / 256, 256, 0, stream>>>(
        cls0, reg0, obj0, cls1, reg1, obj1, cls2, reg2, obj2,
        wboxes, wscores, wlabels);

    nms_kernel<<<BATCH, NT, 0, stream>>>(wboxes, wscores, wlabels, (float*)d_out);
}

// Round 3
// 367.551 us; speedup vs baseline: 1.4556x; 1.3438x over previous
//
#include <hip/hip_runtime.h>
#include <cmath>

#define BATCH 32
#define NA 8400
#define NC 80
#define MAXDET 100
#define NMSTHR 0.65f
#define SCTHR 0.01f
#define NEG_INF (-INFINITY)

#define NT 512          // NMS threads per block
#define NW (NT / 64)    // 8 waves per block

__device__ __forceinline__ float stable_sigmoid(float x) {
    if (x >= 0.f) return 1.f / (1.f + expf(-x));
    float e = expf(x);
    return e / (1.f + e);
}

// ---------------- decode ----------------
// One thread per 4 consecutive anchors. Constant W per level -> compiler
// magic-mul division. 4 independent channel-max chains for load pipelining.
template<int HW, int W, int S>
__device__ __forceinline__ void decode_level(
    const float* __restrict__ cls, const float* __restrict__ reg,
    const float* __restrict__ obj, int b, int p, size_t gbase,
    float4* __restrict__ wboxes, float* __restrict__ wscores, int* __restrict__ wlabels)
{
    const float4* cbase = (const float4*)(cls + (size_t)b * NC * HW + p);
    const int hw4 = HW / 4;

    float mq[4][4];
    int   lq[4][4];
    #pragma unroll
    for (int q = 0; q < 4; ++q)
        #pragma unroll
        for (int e = 0; e < 4; ++e) { mq[q][e] = NEG_INF; lq[q][e] = 0; }

    #pragma unroll
    for (int q = 0; q < 4; ++q) {
        #pragma unroll
        for (int c2 = 0; c2 < 20; ++c2) {
            int c = q * 20 + c2;
            float4 v = cbase[(size_t)c * hw4];
            if (v.x > mq[q][0]) { mq[q][0] = v.x; lq[q][0] = c; }
            if (v.y > mq[q][1]) { mq[q][1] = v.y; lq[q][1] = c; }
            if (v.z > mq[q][2]) { mq[q][2] = v.z; lq[q][2] = c; }
            if (v.w > mq[q][3]) { mq[q][3] = v.w; lq[q][3] = c; }
        }
    }
    // merge quarters in order (strict > keeps lowest channel on ties)
    float maxv[4]; int lab[4];
    #pragma unroll
    for (int e = 0; e < 4; ++e) { maxv[e] = mq[0][e]; lab[e] = lq[0][e]; }
    #pragma unroll
    for (int q = 1; q < 4; ++q)
        #pragma unroll
        for (int e = 0; e < 4; ++e)
            if (mq[q][e] > maxv[e]) { maxv[e] = mq[q][e]; lab[e] = lq[q][e]; }

    const float* rb = reg + (size_t)b * 4 * HW + p;
    float4 r0 = *(const float4*)(rb);
    float4 r1 = *(const float4*)(rb + HW);
    float4 r2 = *(const float4*)(rb + 2 * (size_t)HW);
    float4 r3 = *(const float4*)(rb + 3 * (size_t)HW);
    float4 ov = *(const float4*)(obj + (size_t)b * HW + p);

    float rx[4] = {r0.x, r0.y, r0.z, r0.w};
    float ry[4] = {r1.x, r1.y, r1.z, r1.w};
    float rw[4] = {r2.x, r2.y, r2.z, r2.w};
    float rh[4] = {r3.x, r3.y, r3.z, r3.w};
    float ob[4] = {ov.x, ov.y, ov.z, ov.w};

    float sc4[4];
    #pragma unroll
    for (int e = 0; e < 4; ++e) {
        int pp = p + e;
        int y = pp / W;          // W constexpr -> magic mul
        int x = pp - y * W;
        float score = stable_sigmoid(maxv[e]) * stable_sigmoid(ob[e]);
        float cx = rx[e] * (float)S + (float)x * (float)S;
        float cy = ry[e] * (float)S + (float)y * (float)S;
        float bw = expf(rw[e]) * (float)S;
        float bh = expf(rh[e]) * (float)S;
        wboxes[gbase + e] = make_float4(cx - bw * 0.5f, cy - bh * 0.5f,
                                        cx + bw * 0.5f, cy + bh * 0.5f);
        sc4[e] = score;
    }
    *(float4*)(wscores + gbase) = make_float4(sc4[0], sc4[1], sc4[2], sc4[3]);
    *(int4*)(wlabels + gbase)   = make_int4(lab[0], lab[1], lab[2], lab[3]);
}

__global__ __launch_bounds__(256, 2) void decode_kernel(
    const float* __restrict__ cls0, const float* __restrict__ reg0, const float* __restrict__ obj0,
    const float* __restrict__ cls1, const float* __restrict__ reg1, const float* __restrict__ obj1,
    const float* __restrict__ cls2, const float* __restrict__ reg2, const float* __restrict__ obj2,
    float4* __restrict__ wboxes, float* __restrict__ wscores, int* __restrict__ wlabels)
{
    int a = blockIdx.x * blockDim.x + threadIdx.x;
    if (a >= BATCH * (NA / 4)) return;
    int b = a / (NA / 4);
    int j = (a - b * (NA / 4)) * 4;
    size_t gbase = (size_t)b * NA + j;

    if (j < 6400)
        decode_level<6400, 80, 8>(cls0, reg0, obj0, b, j, gbase, wboxes, wscores, wlabels);
    else if (j < 8000)
        decode_level<1600, 40, 16>(cls1, reg1, obj1, b, j - 6400, gbase, wboxes, wscores, wlabels);
    else
        decode_level<400, 20, 32>(cls2, reg2, obj2, b, j - 8000, gbase, wboxes, wscores, wlabels);
}

// ---------------- NMS ----------------
// One block per image, exact sequential-greedy reference semantics.
// All per-anchor state in NAMED SCALARS (macro-generated) so the compiler
// cannot demote to scratch (round-1/2 showed VGPR_Count=76 => arrays spilled).

#define KREP(M) M(0) M(1) M(2) M(3) M(4) M(5) M(6) M(7) M(8) M(9) M(10) M(11) M(12) M(13) M(14) M(15) M(16)

__global__ __launch_bounds__(NT, 2) void nms_kernel(
    const float4* __restrict__ wboxes, const float* __restrict__ wscores,
    const int* __restrict__ wlabels, float* __restrict__ out)
{
    int b = blockIdx.x;
    int t = threadIdx.x;
    const float4* boxes  = wboxes  + (size_t)b * NA;
    const float*  scores = wscores + (size_t)b * NA;
    const int*    labels = wlabels + (size_t)b * NA;

    __shared__ float2 s_cand[2][NW];   // .x = score, .y = idx (int bits)
    __shared__ float4 s_cbox[2][NW];   // owner's offset box
    __shared__ float  s_red[NW];
    __shared__ float  s_off;
    __shared__ int    s_keep[MAXDET];
    __shared__ float  s_ksc[MAXDET];

    // per-anchor state: offset box, live score, 0.65*(area+1e-6)
    #define DECLK(i) float bxx##i, bxy##i, bxz##i, bxw##i, lv##i, cc##i;
    KREP(DECLK)

    // pass 1: load raw boxes, reduce max |coord|
    float m = 0.f;
    #define LOADK(i) { int j = t + (i) * NT; \
        if (j < NA) { float4 v = boxes[j]; \
            bxx##i = v.x; bxy##i = v.y; bxz##i = v.z; bxw##i = v.w; \
            m = fmaxf(m, fmaxf(fmaxf(fabsf(v.x), fabsf(v.y)), \
                               fmaxf(fabsf(v.z), fabsf(v.w)))); } \
        else { bxx##i = 0.f; bxy##i = 0.f; bxz##i = 0.f; bxw##i = 0.f; } }
    KREP(LOADK)

    #pragma unroll
    for (int o = 32; o >= 1; o >>= 1) m = fmaxf(m, __shfl_xor(m, o));
    if ((t & 63) == 0) s_red[t >> 6] = m;
    __syncthreads();
    if (t == 0) {
        float mm = 0.f;
        for (int wv = 0; wv < NW; ++wv) mm = fmaxf(mm, s_red[wv]);
        s_off = mm + 1.f;
    }
    __syncthreads();
    float offset = s_off;

    // pass 2: class offsets, live init, suppression constants
    #define OFFK(i) { int j = t + (i) * NT; \
        if (j < NA) { \
            float lo = (float)labels[j] * offset; \
            bxx##i += lo; bxy##i += lo; bxz##i += lo; bxw##i += lo; \
            float sc = scores[j]; \
            lv##i = (sc >= SCTHR) ? sc : NEG_INF; \
        } else lv##i = NEG_INF; \
        cc##i = NMSTHR * ((bxz##i - bxx##i) * (bxw##i - bxy##i) + 1e-6f); }
    KREP(OFFK)

    // cached per-thread argmax (with box ride-along)
    float cls = NEG_INF;
    int   clj = -1;
    float cb0 = 0.f, cb1 = 0.f, cb2 = 0.f, cb3 = 0.f;
    bool  dirty = true;

    #define ARGK(i) { if (lv##i > cls) { cls = lv##i; clj = t + (i) * NT; \
        cb0 = bxx##i; cb1 = bxy##i; cb2 = bxz##i; cb3 = bxw##i; } }

    int par = 0;
    for (int it = 0; it < MAXDET; ++it) {
        if (dirty) {
            cls = NEG_INF; clj = -1;
            KREP(ARGK)
            dirty = false;
        }
        // wave butterfly on (score, idx); tie -> lower idx
        float ls = cls;
        int   lj = clj;
        #pragma unroll
        for (int o = 32; o >= 1; o >>= 1) {
            float os = __shfl_xor(ls, o);
            int   oj = __shfl_xor(lj, o);
            if (os > ls || (os == ls && (unsigned)oj < (unsigned)lj)) { ls = os; lj = oj; }
        }
        int wv = t >> 6;
        if (lj >= 0) {
            if (clj == lj) {   // unique owner lane of the wave winner
                s_cand[par][wv] = make_float2(ls, __int_as_float(lj));
                s_cbox[par][wv] = make_float4(cb0, cb1, cb2, cb3);
            }
        } else if ((t & 63) == 0) {
            s_cand[par][wv] = make_float2(NEG_INF, __int_as_float(-1));
        }
        __syncthreads();   // the only barrier per iteration

        // lane-parallel reduce of NW=8 candidates; every lane converges
        float2 c = s_cand[par][t & 7];
        float bs = c.x;
        int   bj = __float_as_int(c.y);
        #pragma unroll
        for (int o = 1; o <= 4; o <<= 1) {
            float os = __shfl_xor(bs, o);
            int   oj = __shfl_xor(bj, o);
            if (os > bs || (os == bs && (unsigned)oj < (unsigned)bj)) { bs = os; bj = oj; }
        }
        int bwv = (bj & (NT - 1)) >> 6;   // winner's wave slot (bj=-1 -> 7, harmless)
        float4 bb = s_cbox[par][bwv];
        if (t == 0) { s_keep[it] = bj; s_ksc[it] = bs; }

        // suppression: division-free IoU test; self suppresses via IoU≈1
        float a1 = (bb.z - bb.x) * (bb.w - bb.y);
        float U  = NMSTHR * a1;
        #define SUPK(i) { \
            float tlx = fmaxf(bb.x, bxx##i); float tly = fmaxf(bb.y, bxy##i); \
            float brx = fminf(bb.z, bxz##i); float bry = fminf(bb.w, bxw##i); \
            float ww = fmaxf(brx - tlx, 0.f); float hh = fmaxf(bry - tly, 0.f); \
            float inter = ww * hh; \
            if (fmaf(inter, 1.f + NMSTHR, -cc##i) > U) { \
                dirty |= (lv##i == cls); lv##i = NEG_INF; } }
        KREP(SUPK)
        par ^= 1;
    }
    __syncthreads();

    // epilogue: boxes/scores/labels/valid, all fp32
    if (t < MAXDET) {
        float ks = s_ksc[t];
        int   kj = s_keep[t];
        bool valid = (ks > NEG_INF) && (kj >= 0);
        float4 obx = make_float4(0.f, 0.f, 0.f, 0.f);
        float osc = 0.f, olab = -1.f, oval = 0.f;
        if (valid) {
            obx  = boxes[kj];          // raw (non-offset) box
            osc  = ks;
            olab = (float)labels[kj];
            oval = 1.f;
        }
        float* ob = out + ((size_t)b * MAXDET + t) * 4;
        ob[0] = obx.x; ob[1] = obx.y; ob[2] = obx.z; ob[3] = obx.w;
        out[BATCH * MAXDET * 4 + b * MAXDET + t] = osc;
        out[BATCH * MAXDET * 5 + b * MAXDET + t] = olab;
        out[BATCH * MAXDET * 6 + b * MAXDET + t] = oval;
    }
}

extern "C" void kernel_launch(void* const* d_in, const int* in_sizes, int n_in,
                              void* d_out, int out_size, void* d_ws, size_t ws_size,
                              hipStream_t stream) {
    // setup_inputs() dict order: cls0, reg0, obj0, cls1, reg1, obj1, cls2, reg2, obj2
    const float* cls0 = (const float*)d_in[0];
    const float* reg0 = (const float*)d_in[1];
    const float* obj0 = (const float*)d_in[2];
    const float* cls1 = (const float*)d_in[3];
    const float* reg1 = (const float*)d_in[4];
    const float* obj1 = (const float*)d_in[5];
    const float* cls2 = (const float*)d_in[6];
    const float* reg2 = (const float*)d_in[7];
    const float* obj2 = (const float*)d_in[8];

    char* ws = (char*)d_ws;
    float4* wboxes  = (float4*)ws;
    float*  wscores = (float*)(ws + (size_t)BATCH * NA * sizeof(float4));
    int*    wlabels = (int*)(ws + (size_t)BATCH * NA * (sizeof(float4) + sizeof(float)));

    int total4 = BATCH * (NA / 4);   // 67200
    decode_kernel<<<(total4 + 255) / 256, 256, 0, stream>>>(
        cls0, reg0, obj0, cls1, reg1, obj1, cls2, reg2, obj2,
        wboxes, wscores, wlabels);

    nms_kernel<<<BATCH, NT, 0, stream>>>(wboxes, wscores, wlabels, (float*)d_out);
}

// Round 4
// 358.223 us; speedup vs baseline: 1.4935x; 1.0260x over previous
//
#include <hip/hip_runtime.h>
#include <cmath>

#define BATCH 32
#define NA 8400
#define NC 80
#define MAXDET 100
#define NMSTHR 0.65f
#define SCTHR 0.01f
#define NEG_INF (-INFINITY)

#define NT 1024         // NMS threads per block
#define NW (NT / 64)    // 16 waves per block
#define CH 9            // ceil(8400/1024)
#define KTAIL (NA - 8 * NT)   // 208: threads with a 9th element

__device__ __forceinline__ float stable_sigmoid(float x) {
    if (x >= 0.f) return 1.f / (1.f + expf(-x));
    float e = expf(x);
    return e / (1.f + e);
}

// ---------------- decode: one thread per anchor ----------------
// 1050 blocks x 256 -> ~8 waves/SIMD of latency hiding. Scalar loads
// coalesce across consecutive anchors within each channel plane.
template<int HW, int W, int S>
__device__ __forceinline__ void decode_one(
    const float* __restrict__ cls, const float* __restrict__ reg,
    const float* __restrict__ obj, int b, int p, size_t gidx,
    float4* __restrict__ wboxes, float* __restrict__ wscores, int* __restrict__ wlabels)
{
    const float* cbase = cls + (size_t)b * NC * HW + p;

    // 4 blocked chains of 20 channels (in-order merge keeps first-max tiebreak)
    float mq[4]; int lq[4];
    #pragma unroll
    for (int q = 0; q < 4; ++q) { mq[q] = NEG_INF; lq[q] = 0; }
    #pragma unroll
    for (int q = 0; q < 4; ++q) {
        #pragma unroll
        for (int c2 = 0; c2 < 20; ++c2) {
            int c = q * 20 + c2;
            float v = cbase[(size_t)c * HW];
            if (v > mq[q]) { mq[q] = v; lq[q] = c; }
        }
    }
    float maxv = mq[0]; int lab = lq[0];
    #pragma unroll
    for (int q = 1; q < 4; ++q)
        if (mq[q] > maxv) { maxv = mq[q]; lab = lq[q]; }

    const float* rb = reg + (size_t)b * 4 * HW + p;
    float r0 = rb[0];
    float r1 = rb[HW];
    float r2 = rb[2 * (size_t)HW];
    float r3 = rb[3 * (size_t)HW];
    float ov = obj[(size_t)b * HW + p];

    int y = p / W;            // W constexpr -> magic mul
    int x = p - y * W;
    float score = stable_sigmoid(maxv) * stable_sigmoid(ov);
    float cx = r0 * (float)S + (float)x * (float)S;
    float cy = r1 * (float)S + (float)y * (float)S;
    float bw = expf(r2) * (float)S;
    float bh = expf(r3) * (float)S;

    wboxes[gidx]  = make_float4(cx - bw * 0.5f, cy - bh * 0.5f,
                                cx + bw * 0.5f, cy + bh * 0.5f);
    wscores[gidx] = score;
    wlabels[gidx] = lab;
}

__global__ __launch_bounds__(256) void decode_kernel(
    const float* __restrict__ cls0, const float* __restrict__ reg0, const float* __restrict__ obj0,
    const float* __restrict__ cls1, const float* __restrict__ reg1, const float* __restrict__ obj1,
    const float* __restrict__ cls2, const float* __restrict__ reg2, const float* __restrict__ obj2,
    float4* __restrict__ wboxes, float* __restrict__ wscores, int* __restrict__ wlabels)
{
    int gid = blockIdx.x * blockDim.x + threadIdx.x;   // grid == BATCH*NA exactly
    int b = gid / NA;
    int j = gid - b * NA;
    size_t gidx = (size_t)gid;

    if (j < 6400)
        decode_one<6400, 80, 8>(cls0, reg0, obj0, b, j, gidx, wboxes, wscores, wlabels);
    else if (j < 8000)
        decode_one<1600, 40, 16>(cls1, reg1, obj1, b, j - 6400, gidx, wboxes, wscores, wlabels);
    else
        decode_one<400, 20, 32>(cls2, reg2, obj2, b, j - 8000, gidx, wboxes, wscores, wlabels);
}

// ---------------- NMS: one block (1024 thr) per image ----------------
// Exact sequential-greedy reference semantics. Per-thread state is only
// 9 anchors (vs 17 before): 9*(box4+lv+cc)=54 floats -> fits in the
// 128-VGPR budget of launch_bounds(1024,4); 4 waves/SIMD latency hiding.

#define KREP(M) M(0) M(1) M(2) M(3) M(4) M(5) M(6) M(7) M(8)

__global__ __launch_bounds__(NT, 4) void nms_kernel(
    const float4* __restrict__ wboxes, const float* __restrict__ wscores,
    const int* __restrict__ wlabels, float* __restrict__ out)
{
    int b = blockIdx.x;
    int t = threadIdx.x;
    const float4* boxes  = wboxes  + (size_t)b * NA;
    const float*  scores = wscores + (size_t)b * NA;
    const int*    labels = wlabels + (size_t)b * NA;

    __shared__ float2 s_cand[2][NW];   // .x = score, .y = idx (int bits)
    __shared__ float4 s_cbox[2][NW];   // owner's offset box
    __shared__ float  s_red[NW];
    __shared__ float  s_off;
    __shared__ int    s_keep[MAXDET];
    __shared__ float  s_ksc[MAXDET];

    // per-anchor state: offset box, live score, 0.65*(area+1e-6)
    #define DECLK(i) float bxx##i, bxy##i, bxz##i, bxw##i, lv##i, cc##i;
    KREP(DECLK)

    // pass 1: load raw boxes (k<8 always in-bounds; k==8 iff t<KTAIL), max|coord|
    float m = 0.f;
    #define LOADK(i) { int j = t + (i) * NT; \
        if ((i) < 8 || t < KTAIL) { float4 v = boxes[j]; \
            bxx##i = v.x; bxy##i = v.y; bxz##i = v.z; bxw##i = v.w; \
            m = fmaxf(m, fmaxf(fmaxf(fabsf(v.x), fabsf(v.y)), \
                               fmaxf(fabsf(v.z), fabsf(v.w)))); } \
        else { bxx##i = 0.f; bxy##i = 0.f; bxz##i = 0.f; bxw##i = 0.f; } }
    KREP(LOADK)

    #pragma unroll
    for (int o = 32; o >= 1; o >>= 1) m = fmaxf(m, __shfl_xor(m, o));
    if ((t & 63) == 0) s_red[t >> 6] = m;
    __syncthreads();
    if (t == 0) {
        float mm = 0.f;
        for (int wv = 0; wv < NW; ++wv) mm = fmaxf(mm, s_red[wv]);
        s_off = mm + 1.f;
    }
    __syncthreads();
    float offset = s_off;

    // pass 2: class offsets, live init, suppression constants
    #define OFFK(i) { int j = t + (i) * NT; \
        if ((i) < 8 || t < KTAIL) { \
            float lo = (float)labels[j] * offset; \
            bxx##i += lo; bxy##i += lo; bxz##i += lo; bxw##i += lo; \
            float sc = scores[j]; \
            lv##i = (sc >= SCTHR) ? sc : NEG_INF; \
        } else lv##i = NEG_INF; \
        cc##i = NMSTHR * ((bxz##i - bxx##i) * (bxw##i - bxy##i) + 1e-6f); }
    KREP(OFFK)

    // cached per-thread argmax with box ride-along
    float cls = NEG_INF;
    int   clj = -1;
    float cb0 = 0.f, cb1 = 0.f, cb2 = 0.f, cb3 = 0.f;
    bool  dirty = true;

    #define ARGK(i) { if (lv##i > cls) { cls = lv##i; clj = t + (i) * NT; \
        cb0 = bxx##i; cb1 = bxy##i; cb2 = bxz##i; cb3 = bxw##i; } }

    int par = 0;
    for (int it = 0; it < MAXDET; ++it) {
        if (dirty) {
            cls = NEG_INF; clj = -1;
            KREP(ARGK)
            dirty = false;
        }
        // wave butterfly on (score, idx); tie -> lower idx
        float ls = cls;
        int   lj = clj;
        #pragma unroll
        for (int o = 32; o >= 1; o >>= 1) {
            float os = __shfl_xor(ls, o);
            int   oj = __shfl_xor(lj, o);
            if (os > ls || (os == ls && (unsigned)oj < (unsigned)lj)) { ls = os; lj = oj; }
        }
        int wv = t >> 6;
        if (lj >= 0) {
            if (clj == lj) {   // unique owner lane of the wave winner
                s_cand[par][wv] = make_float2(ls, __int_as_float(lj));
                s_cbox[par][wv] = make_float4(cb0, cb1, cb2, cb3);
            }
        } else if ((t & 63) == 0) {
            s_cand[par][wv] = make_float2(NEG_INF, __int_as_float(-1));
        }
        __syncthreads();   // the only barrier per iteration

        // lane-parallel reduce of NW=16 candidates; all lanes converge
        float2 c = s_cand[par][t & (NW - 1)];
        float bs = c.x;
        int   bj = __float_as_int(c.y);
        #pragma unroll
        for (int o = 1; o <= NW / 2; o <<= 1) {
            float os = __shfl_xor(bs, o);
            int   oj = __shfl_xor(bj, o);
            if (os > bs || (os == bs && (unsigned)oj < (unsigned)bj)) { bs = os; bj = oj; }
        }
        int bwv = (bj & (NT - 1)) >> 6;   // winner's wave slot (bj=-1 harmless)
        float4 bb = s_cbox[par][bwv];
        if (t == 0) { s_keep[it] = bj; s_ksc[it] = bs; }

        // suppression: division-free IoU test; self suppresses via IoU≈1
        float a1 = (bb.z - bb.x) * (bb.w - bb.y);
        float U  = NMSTHR * a1;
        #define SUPK(i) { \
            float tlx = fmaxf(bb.x, bxx##i); float tly = fmaxf(bb.y, bxy##i); \
            float brx = fminf(bb.z, bxz##i); float bry = fminf(bb.w, bxw##i); \
            float ww = fmaxf(brx - tlx, 0.f); float hh = fmaxf(bry - tly, 0.f); \
            float inter = ww * hh; \
            if (fmaf(inter, 1.f + NMSTHR, -cc##i) > U) { \
                dirty |= (lv##i == cls); lv##i = NEG_INF; } }
        KREP(SUPK)
        par ^= 1;
    }
    __syncthreads();

    // epilogue: boxes/scores/labels/valid, all fp32
    if (t < MAXDET) {
        float ks = s_ksc[t];
        int   kj = s_keep[t];
        bool valid = (ks > NEG_INF) && (kj >= 0);
        float4 obx = make_float4(0.f, 0.f, 0.f, 0.f);
        float osc = 0.f, olab = -1.f, oval = 0.f;
        if (valid) {
            obx  = boxes[kj];          // raw (non-offset) box
            osc  = ks;
            olab = (float)labels[kj];
            oval = 1.f;
        }
        float* ob = out + ((size_t)b * MAXDET + t) * 4;
        ob[0] = obx.x; ob[1] = obx.y; ob[2] = obx.z; ob[3] = obx.w;
        out[BATCH * MAXDET * 4 + b * MAXDET + t] = osc;
        out[BATCH * MAXDET * 5 + b * MAXDET + t] = olab;
        out[BATCH * MAXDET * 6 + b * MAXDET + t] = oval;
    }
}

extern "C" void kernel_launch(void* const* d_in, const int* in_sizes, int n_in,
                              void* d_out, int out_size, void* d_ws, size_t ws_size,
                              hipStream_t stream) {
    // setup_inputs() dict order: cls0, reg0, obj0, cls1, reg1, obj1, cls2, reg2, obj2
    const float* cls0 = (const float*)d_in[0];
    const float* reg0 = (const float*)d_in[1];
    const float* obj0 = (const float*)d_in[2];
    const float* cls1 = (const float*)d_in[3];
    const float* reg1 = (const float*)d_in[4];
    const float* obj1 = (const float*)d_in[5];
    const float* cls2 = (const float*)d_in[6];
    const float* reg2 = (const float*)d_in[7];
    const float* obj2 = (const float*)d_in[8];

    char* ws = (char*)d_ws;
    float4* wboxes  = (float4*)ws;
    float*  wscores = (float*)(ws + (size_t)BATCH * NA * sizeof(float4));
    int*    wlabels = (int*)(ws + (size_t)BATCH * NA * (sizeof(float4) + sizeof(float)));

    int total = BATCH * NA;   // 268800 = 1050 * 256 exactly
    decode_kernel<<<total / 256, 256, 0, stream>>>(
        cls0, reg0, obj0, cls1, reg1, obj1, cls2, reg2, obj2,
        wboxes, wscores, wlabels);

    nms_kernel<<<BATCH, NT, 0, stream>>>(wboxes, wscores, wlabels, (float*)d_out);
}

// Round 5
// 332.447 us; speedup vs baseline: 1.6093x; 1.0775x over previous
//
#include <hip/hip_runtime.h>
#include <cmath>

typedef unsigned int uint;
typedef unsigned long long ull;

#define BATCH 32
#define NA 8400
#define NC 80
#define MAXDET 100
#define NMSTHR 0.65f
#define SCTHR 0.01f
#define NEG_INF (-INFINITY)

#define NT 1024         // NMS threads per block
#define NW (NT / 64)
#define EPT 9           // ceil(NA / NT)
#define NBINS 4096      // histogram bins on key[31:20]
#define CAP 512         // max candidates per sorted window

__device__ __forceinline__ float stable_sigmoid(float x) {
    if (x >= 0.f) return 1.f / (1.f + expf(-x));
    float e = expf(x);
    return e / (1.f + e);
}

// ---------------- decode: one thread per anchor (unchanged, bit-exact) ----------------
template<int HW, int W, int S>
__device__ __forceinline__ void decode_one(
    const float* __restrict__ cls, const float* __restrict__ reg,
    const float* __restrict__ obj, int b, int p, size_t gidx,
    float4* __restrict__ wboxes, float* __restrict__ wscores, int* __restrict__ wlabels)
{
    const float* cbase = cls + (size_t)b * NC * HW + p;

    float mq[4]; int lq[4];
    #pragma unroll
    for (int q = 0; q < 4; ++q) { mq[q] = NEG_INF; lq[q] = 0; }
    #pragma unroll
    for (int q = 0; q < 4; ++q) {
        #pragma unroll
        for (int c2 = 0; c2 < 20; ++c2) {
            int c = q * 20 + c2;
            float v = cbase[(size_t)c * HW];
            if (v > mq[q]) { mq[q] = v; lq[q] = c; }
        }
    }
    float maxv = mq[0]; int lab = lq[0];
    #pragma unroll
    for (int q = 1; q < 4; ++q)
        if (mq[q] > maxv) { maxv = mq[q]; lab = lq[q]; }

    const float* rb = reg + (size_t)b * 4 * HW + p;
    float r0 = rb[0];
    float r1 = rb[HW];
    float r2 = rb[2 * (size_t)HW];
    float r3 = rb[3 * (size_t)HW];
    float ov = obj[(size_t)b * HW + p];

    int y = p / W;
    int x = p - y * W;
    float score = stable_sigmoid(maxv) * stable_sigmoid(ov);
    float cx = r0 * (float)S + (float)x * (float)S;
    float cy = r1 * (float)S + (float)y * (float)S;
    float bw = expf(r2) * (float)S;
    float bh = expf(r3) * (float)S;

    wboxes[gidx]  = make_float4(cx - bw * 0.5f, cy - bh * 0.5f,
                                cx + bw * 0.5f, cy + bh * 0.5f);
    wscores[gidx] = score;
    wlabels[gidx] = lab;
}

__global__ __launch_bounds__(256) void decode_kernel(
    const float* __restrict__ cls0, const float* __restrict__ reg0, const float* __restrict__ obj0,
    const float* __restrict__ cls1, const float* __restrict__ reg1, const float* __restrict__ obj1,
    const float* __restrict__ cls2, const float* __restrict__ reg2, const float* __restrict__ obj2,
    float4* __restrict__ wboxes, float* __restrict__ wscores, int* __restrict__ wlabels)
{
    int gid = blockIdx.x * blockDim.x + threadIdx.x;
    int b = gid / NA;
    int j = gid - b * NA;
    size_t gidx = (size_t)gid;

    if (j < 6400)
        decode_one<6400, 80, 8>(cls0, reg0, obj0, b, j, gidx, wboxes, wscores, wlabels);
    else if (j < 8000)
        decode_one<1600, 40, 16>(cls1, reg1, obj1, b, j - 6400, gidx, wboxes, wscores, wlabels);
    else
        decode_one<400, 20, 32>(cls2, reg2, obj2, b, j - 8000, gidx, wboxes, wscores, wlabels);
}

// ---------------- NMS via sorted walk (exact greedy-NMS equivalence) ----------------
// Greedy NMS == walk candidates in (score desc, idx asc) order; keep iff
// IoU <= thr vs every previously-KEPT box; stop at MAXDET. Windows of bins
// (top-12-bit key histogram) preserve global order; within-window bitonic
// sort on (key,idx) gives the exact total order.
__global__ __launch_bounds__(NT) void nms_kernel(
    const float4* __restrict__ wboxes, const float* __restrict__ wscores,
    const int* __restrict__ wlabels, float* __restrict__ out)
{
    int b = blockIdx.x;
    int t = threadIdx.x;
    const float4* boxes  = wboxes  + (size_t)b * NA;
    const float*  scores = wscores + (size_t)b * NA;
    const int*    labels = wlabels + (size_t)b * NA;

    __shared__ uint  s_keys[NA];          // ~scorebits, 0xFFFFFFFF = invalid
    __shared__ uint  s_hist[NBINS];
    __shared__ uint  s_cum[NBINS + 1];    // exclusive prefix
    __shared__ uint  s_part[NT];
    __shared__ ull   s_skey[CAP];
    __shared__ float s_kbox[MAXDET][4];   // kept OFFSET boxes
    __shared__ float s_ka1[MAXDET];       // kept areas (offset coords)
    __shared__ int   s_kidx[MAXDET];
    __shared__ float s_kscr[MAXDET];
    __shared__ int   s_klab[MAXDET];
    __shared__ float s_red[NW];
    __shared__ float s_off;
    __shared__ int   s_kept, s_winlo, s_winhi, s_nsel;

    // ---- offset = max|coord| over ALL boxes + 1 ----
    float m = 0.f;
    #pragma unroll
    for (int w = 0; w < EPT; ++w) {
        int e = t + w * NT;
        if (e < NA) {
            float4 v = boxes[e];
            m = fmaxf(m, fmaxf(fmaxf(fabsf(v.x), fabsf(v.y)),
                               fmaxf(fabsf(v.z), fabsf(v.w))));
        }
    }
    #pragma unroll
    for (int o = 32; o >= 1; o >>= 1) m = fmaxf(m, __shfl_xor(m, o));
    if ((t & 63) == 0) s_red[t >> 6] = m;
    __syncthreads();
    if (t == 0) {
        float mm = 0.f;
        for (int wv = 0; wv < NW; ++wv) mm = fmaxf(mm, s_red[wv]);
        s_off = mm + 1.f;
        s_kept = 0;
        s_winlo = 0;
    }

    // ---- keys + histogram ----
    #pragma unroll
    for (int w = 0; w < EPT; ++w) {
        int e = t + w * NT;
        if (e < NA) {
            float sc = scores[e];
            s_keys[e] = (sc >= SCTHR) ? ~__float_as_uint(sc) : 0xFFFFFFFFu;
        }
    }
    for (int i = t; i < NBINS; i += NT) s_hist[i] = 0;
    __syncthreads();
    float off = s_off;
    #pragma unroll
    for (int w = 0; w < EPT; ++w) {
        int e = t + w * NT;
        if (e < NA) {
            uint k = s_keys[e];
            if (k != 0xFFFFFFFFu) atomicAdd(&s_hist[k >> 20], 1u);
        }
    }
    __syncthreads();

    // ---- exclusive scan over 4096 bins (4 bins/thread + Hillis-Steele) ----
    uint l0 = s_hist[4 * t], l1 = s_hist[4 * t + 1],
         l2 = s_hist[4 * t + 2], l3 = s_hist[4 * t + 3];
    s_part[t] = l0 + l1 + l2 + l3;
    __syncthreads();
    for (int o = 1; o < NT; o <<= 1) {
        uint v = (t >= o) ? s_part[t - o] : 0u;
        __syncthreads();
        s_part[t] += v;
        __syncthreads();
    }
    uint base = (t > 0) ? s_part[t - 1] : 0u;
    s_cum[4 * t]     = base;
    s_cum[4 * t + 1] = base + l0;
    s_cum[4 * t + 2] = base + l0 + l1;
    s_cum[4 * t + 3] = base + l0 + l1 + l2;
    if (t == NT - 1) s_cum[NBINS] = s_part[NT - 1];

    // ---- window loop (typically runs once) ----
    for (;;) {
        __syncthreads();
        int kept = s_kept, winlo = s_winlo;
        uint remaining = s_cum[NBINS] - s_cum[winlo];
        if (kept >= MAXDET || winlo >= NBINS || remaining == 0u) break;
        if (t == 0) {
            int hi = winlo;
            while (hi < NBINS && (s_cum[hi + 1] - s_cum[winlo]) <= (uint)CAP) ++hi;
            if (hi == winlo) hi = winlo + 1;   // pathological giant bin: clamp
            s_winhi = hi;
            s_nsel = 0;
        }
        if (t < CAP) s_skey[t] = ~0ull;
        __syncthreads();
        int winhi = s_winhi;

        // compact window candidates
        #pragma unroll
        for (int w = 0; w < EPT; ++w) {
            int e = t + w * NT;
            if (e < NA) {
                uint k = s_keys[e];
                if (k != 0xFFFFFFFFu) {
                    int bin = (int)(k >> 20);
                    if (bin >= winlo && bin < winhi) {
                        int pos = atomicAdd(&s_nsel, 1);
                        if (pos < CAP) s_skey[pos] = ((ull)k << 32) | (uint)e;
                    }
                }
            }
        }
        __syncthreads();
        int nsel = s_nsel; if (nsel > CAP) nsel = CAP;

        // bitonic sort CAP entries ascending (pads sort last); exact total order
        for (int k2 = 2; k2 <= CAP; k2 <<= 1) {
            for (int j = k2 >> 1; j > 0; j >>= 1) {
                __syncthreads();
                if (t < CAP) {
                    int p = t ^ j;
                    if (p > t) {
                        ull a = s_skey[t], bb = s_skey[p];
                        bool up = ((t & k2) == 0);
                        if ((a > bb) == up) { s_skey[t] = bb; s_skey[p] = a; }
                    }
                }
            }
        }
        __syncthreads();

        // sorted walk on wave 0
        if (t < 64) {
            int lane = t;
            int kept2 = s_kept;
            for (int cb = 0; cb < nsel && kept2 < MAXDET; cb += 64) {
                int ci = cb + lane;
                ull sk = (ci < nsel) ? s_skey[ci] : ~0ull;
                bool has = (sk != ~0ull);
                int idx = 0, lab = 0;
                float sc = 0.f, c0 = 0.f, c1 = 0.f, c2 = 0.f, c3 = 0.f, ca = 0.f;
                if (has) {
                    idx = (int)(sk & 0xFFFFFFFFull);
                    sc  = __uint_as_float(~(uint)(sk >> 32));   // exact score bits
                    float4 rb = boxes[idx];
                    lab = labels[idx];
                    float lo = (float)lab * off;
                    c0 = rb.x + lo; c1 = rb.y + lo; c2 = rb.z + lo; c3 = rb.w + lo;
                    ca = (c2 - c0) * (c3 - c1);
                    // test vs already-kept set (exact reference IoU + compare)
                    for (int q = 0; q < kept2; ++q) {
                        float tlx = fmaxf(s_kbox[q][0], c0);
                        float tly = fmaxf(s_kbox[q][1], c1);
                        float brx = fminf(s_kbox[q][2], c2);
                        float bry = fminf(s_kbox[q][3], c3);
                        float ww = fmaxf(brx - tlx, 0.f);
                        float hh = fmaxf(bry - tly, 0.f);
                        float inter = ww * hh;
                        float iou = inter / (s_ka1[q] + ca - inter + 1e-6f);
                        if (iou > NMSTHR) { has = false; break; }
                    }
                }
                // intra-chunk resolution: first alive (== global next-best) is kept
                ull am = __ballot(has);
                while (am && kept2 < MAXDET) {
                    int f = __ffsll(am) - 1;
                    float f0 = __shfl(c0, f), f1 = __shfl(c1, f);
                    float f2 = __shfl(c2, f), f3 = __shfl(c3, f);
                    float fa = __shfl(ca, f);
                    int   fidx = __shfl(idx, f);
                    int   flab = __shfl(lab, f);
                    float fsc  = __shfl(sc, f);
                    if (lane == 0) {
                        s_kbox[kept2][0] = f0; s_kbox[kept2][1] = f1;
                        s_kbox[kept2][2] = f2; s_kbox[kept2][3] = f3;
                        s_ka1[kept2] = fa; s_kidx[kept2] = fidx;
                        s_kscr[kept2] = fsc; s_klab[kept2] = flab;
                    }
                    kept2++;
                    if (lane == f) has = false;
                    if (has) {
                        float tlx = fmaxf(f0, c0), tly = fmaxf(f1, c1);
                        float brx = fminf(f2, c2), bry = fminf(f3, c3);
                        float ww = fmaxf(brx - tlx, 0.f), hh = fmaxf(bry - tly, 0.f);
                        float inter = ww * hh;
                        float iou = inter / (fa + ca - inter + 1e-6f);
                        if (iou > NMSTHR) has = false;
                    }
                    am = __ballot(has);
                }
            }
            if (lane == 0) s_kept = kept2;
        }
        __syncthreads();
        if (t == 0) s_winlo = s_winhi;
    }
    __syncthreads();

    // ---- epilogue: boxes/scores/labels/valid (fp32) ----
    if (t < MAXDET) {
        int kept = s_kept;
        float4 obx = make_float4(0.f, 0.f, 0.f, 0.f);
        float osc = 0.f, olab = -1.f, oval = 0.f;
        if (t < kept) {
            int idx = s_kidx[t];
            obx  = boxes[idx];              // raw (non-offset) box
            osc  = s_kscr[t];
            olab = (float)s_klab[t];
            oval = 1.f;
        }
        float* ob = out + ((size_t)b * MAXDET + t) * 4;
        ob[0] = obx.x; ob[1] = obx.y; ob[2] = obx.z; ob[3] = obx.w;
        out[BATCH * MAXDET * 4 + b * MAXDET + t] = osc;
        out[BATCH * MAXDET * 5 + b * MAXDET + t] = olab;
        out[BATCH * MAXDET * 6 + b * MAXDET + t] = oval;
    }
}

extern "C" void kernel_launch(void* const* d_in, const int* in_sizes, int n_in,
                              void* d_out, int out_size, void* d_ws, size_t ws_size,
                              hipStream_t stream) {
    // setup_inputs() dict order: cls0, reg0, obj0, cls1, reg1, obj1, cls2, reg2, obj2
    const float* cls0 = (const float*)d_in[0];
    const float* reg0 = (const float*)d_in[1];
    const float* obj0 = (const float*)d_in[2];
    const float* cls1 = (const float*)d_in[3];
    const float* reg1 = (const float*)d_in[4];
    const float* obj1 = (const float*)d_in[5];
    const float* cls2 = (const float*)d_in[6];
    const float* reg2 = (const float*)d_in[7];
    const float* obj2 = (const float*)d_in[8];

    char* ws = (char*)d_ws;
    float4* wboxes  = (float4*)ws;
    float*  wscores = (float*)(ws + (size_t)BATCH * NA * sizeof(float4));
    int*    wlabels = (int*)(ws + (size_t)BATCH * NA * (sizeof(float4) + sizeof(float)));

    int total = BATCH * NA;   // 268800 = 1050 * 256 exactly
    decode_kernel<<<total / 256, 256, 0, stream>>>(
        cls0, reg0, obj0, cls1, reg1, obj1, cls2, reg2, obj2,
        wboxes, wscores, wlabels);

    nms_kernel<<<BATCH, NT, 0, stream>>>(wboxes, wscores, wlabels, (float*)d_out);
}

// Round 6
// 178.180 us; speedup vs baseline: 3.0027x; 1.8658x over previous
//
#include <hip/hip_runtime.h>
#include <cmath>

typedef unsigned int uint;
typedef unsigned long long ull;

#define BATCH 32
#define NA 8400
#define NC 80
#define MAXDET 100
#define NMSTHR 0.65f
#define SCTHR 0.01f
#define NEG_INF (-INFINITY)

#define NT 1024         // NMS threads per block
#define NW (NT / 64)
#define EPT 9           // ceil(NA / NT)
#define NBINS 4096      // histogram bins on key[31:20]
#define CAP 512         // max candidates per sorted window

__device__ __forceinline__ float stable_sigmoid(float x) {
    if (x >= 0.f) return 1.f / (1.f + expf(-x));
    float e = expf(x);
    return e / (1.f + e);
}

// ---------------- decode: one thread per anchor (bit-exact, unchanged) ----------------
template<int HW, int W, int S>
__device__ __forceinline__ void decode_one(
    const float* __restrict__ cls, const float* __restrict__ reg,
    const float* __restrict__ obj, int b, int p, size_t gidx,
    float4* __restrict__ wboxes, float* __restrict__ wscores, int* __restrict__ wlabels)
{
    const float* cbase = cls + (size_t)b * NC * HW + p;

    float mq[4]; int lq[4];
    #pragma unroll
    for (int q = 0; q < 4; ++q) { mq[q] = NEG_INF; lq[q] = 0; }
    #pragma unroll
    for (int q = 0; q < 4; ++q) {
        #pragma unroll
        for (int c2 = 0; c2 < 20; ++c2) {
            int c = q * 20 + c2;
            float v = cbase[(size_t)c * HW];
            if (v > mq[q]) { mq[q] = v; lq[q] = c; }
        }
    }
    float maxv = mq[0]; int lab = lq[0];
    #pragma unroll
    for (int q = 1; q < 4; ++q)
        if (mq[q] > maxv) { maxv = mq[q]; lab = lq[q]; }

    const float* rb = reg + (size_t)b * 4 * HW + p;
    float r0 = rb[0];
    float r1 = rb[HW];
    float r2 = rb[2 * (size_t)HW];
    float r3 = rb[3 * (size_t)HW];
    float ov = obj[(size_t)b * HW + p];

    int y = p / W;
    int x = p - y * W;
    float score = stable_sigmoid(maxv) * stable_sigmoid(ov);
    float cx = r0 * (float)S + (float)x * (float)S;
    float cy = r1 * (float)S + (float)y * (float)S;
    float bw = expf(r2) * (float)S;
    float bh = expf(r3) * (float)S;

    wboxes[gidx]  = make_float4(cx - bw * 0.5f, cy - bh * 0.5f,
                                cx + bw * 0.5f, cy + bh * 0.5f);
    wscores[gidx] = score;
    wlabels[gidx] = lab;
}

__global__ __launch_bounds__(256) void decode_kernel(
    const float* __restrict__ cls0, const float* __restrict__ reg0, const float* __restrict__ obj0,
    const float* __restrict__ cls1, const float* __restrict__ reg1, const float* __restrict__ obj1,
    const float* __restrict__ cls2, const float* __restrict__ reg2, const float* __restrict__ obj2,
    float4* __restrict__ wboxes, float* __restrict__ wscores, int* __restrict__ wlabels)
{
    int gid = blockIdx.x * blockDim.x + threadIdx.x;
    int b = gid / NA;
    int j = gid - b * NA;
    size_t gidx = (size_t)gid;

    if (j < 6400)
        decode_one<6400, 80, 8>(cls0, reg0, obj0, b, j, gidx, wboxes, wscores, wlabels);
    else if (j < 8000)
        decode_one<1600, 40, 16>(cls1, reg1, obj1, b, j - 6400, gidx, wboxes, wscores, wlabels);
    else
        decode_one<400, 20, 32>(cls2, reg2, obj2, b, j - 8000, gidx, wboxes, wscores, wlabels);
}

// ---------------- NMS via sorted walk (exact greedy-NMS equivalence) ----------------
__global__ __launch_bounds__(NT) void nms_kernel(
    const float4* __restrict__ wboxes, const float* __restrict__ wscores,
    const int* __restrict__ wlabels, float* __restrict__ out)
{
    int b = blockIdx.x;
    int t = threadIdx.x;
    int lane = t & 63;
    int wv = t >> 6;
    const float4* boxes  = wboxes  + (size_t)b * NA;
    const float*  scores = wscores + (size_t)b * NA;
    const int*    labels = wlabels + (size_t)b * NA;

    __shared__ uint  s_keys[NA];          // ~scorebits, 0xFFFFFFFF = invalid
    __shared__ uint  s_hist[NBINS];
    __shared__ uint  s_cum[NBINS + 1];    // exclusive prefix
    __shared__ uint  s_wsum[NW];
    __shared__ ull   s_skey[CAP];
    __shared__ float s_kbox[MAXDET][4];   // kept OFFSET boxes
    __shared__ float s_ka1[MAXDET];
    __shared__ int   s_kidx[MAXDET];
    __shared__ float s_kscr[MAXDET];
    __shared__ int   s_klab[MAXDET];
    __shared__ float s_red[NW];
    __shared__ float s_off;
    __shared__ int   s_kept, s_winlo, s_winhi, s_nsel;

    // ---- offset = max|coord| over ALL boxes + 1 ----
    float m = 0.f;
    #pragma unroll
    for (int w = 0; w < EPT; ++w) {
        int e = t + w * NT;
        if (e < NA) {
            float4 v = boxes[e];
            m = fmaxf(m, fmaxf(fmaxf(fabsf(v.x), fabsf(v.y)),
                               fmaxf(fabsf(v.z), fabsf(v.w))));
        }
    }
    #pragma unroll
    for (int o = 32; o >= 1; o >>= 1) m = fmaxf(m, __shfl_xor(m, o));
    if (lane == 0) s_red[wv] = m;
    __syncthreads();
    if (t == 0) {
        float mm = 0.f;
        for (int w = 0; w < NW; ++w) mm = fmaxf(mm, s_red[w]);
        s_off = mm + 1.f;
        s_kept = 0;
        s_winlo = 0;
    }

    // ---- keys + histogram ----
    #pragma unroll
    for (int w = 0; w < EPT; ++w) {
        int e = t + w * NT;
        if (e < NA) {
            float sc = scores[e];
            s_keys[e] = (sc >= SCTHR) ? ~__float_as_uint(sc) : 0xFFFFFFFFu;
        }
    }
    for (int i = t; i < NBINS; i += NT) s_hist[i] = 0;
    __syncthreads();
    float off = s_off;
    #pragma unroll
    for (int w = 0; w < EPT; ++w) {
        int e = t + w * NT;
        if (e < NA) {
            uint k = s_keys[e];
            if (k != 0xFFFFFFFFu) atomicAdd(&s_hist[k >> 20], 1u);
        }
    }
    __syncthreads();

    // ---- exclusive scan over 4096 bins: 4 bins/thread + shfl scans ----
    uint l0 = s_hist[4 * t], l1 = s_hist[4 * t + 1],
         l2 = s_hist[4 * t + 2], l3 = s_hist[4 * t + 3];
    uint L = l0 + l1 + l2 + l3;
    uint ls = L;                                  // wave-inclusive scan of L
    #pragma unroll
    for (int o = 1; o < 64; o <<= 1) {
        uint v = __shfl_up(ls, o);
        if (lane >= o) ls += v;
    }
    if (lane == 63) s_wsum[wv] = ls;              // wave totals
    __syncthreads();
    if (t < NW) {                                 // cross-wave exclusive scan (16 vals)
        uint v = s_wsum[t];
        uint vs = v;
        #pragma unroll
        for (int o = 1; o < NW; o <<= 1) {
            uint u = __shfl_up(vs, o);
            if ((t & 63) >= o) vs += u;
        }
        s_wsum[t] = vs - v;
    }
    __syncthreads();
    uint base = s_wsum[wv] + (ls - L);            // exclusive prefix for this thread's 4 bins
    s_cum[4 * t]     = base;
    s_cum[4 * t + 1] = base + l0;
    s_cum[4 * t + 2] = base + l0 + l1;
    s_cum[4 * t + 3] = base + l0 + l1 + l2;
    if (t == NT - 1) s_cum[NBINS] = base + L;

    // ---- window loop (typically runs once) ----
    for (;;) {
        __syncthreads();
        int kept = s_kept, winlo = s_winlo;
        uint remaining = s_cum[NBINS] - s_cum[winlo];
        if (kept >= MAXDET || winlo >= NBINS || remaining == 0u) break;
        if (t == 0) { s_winhi = winlo + 1; s_nsel = 0; }   // giant-bin clamp floor
        if (t < CAP) s_skey[t] = ~0ull;
        __syncthreads();
        // parallel winhi: predicate monotone in i -> atomicMax over qualifying i+1
        uint cl = s_cum[winlo];
        #pragma unroll
        for (int q = 0; q < 4; ++q) {
            int i = t + q * NT;
            if (i >= winlo && i < NBINS && (s_cum[i + 1] - cl) <= (uint)CAP)
                atomicMax(&s_winhi, i + 1);
        }
        __syncthreads();
        int winhi = s_winhi;

        // wave-aggregated compaction of window candidates
        #pragma unroll
        for (int w = 0; w < EPT; ++w) {
            int e = t + w * NT;
            bool q = false;
            uint k = 0;
            if (e < NA) {
                k = s_keys[e];
                if (k != 0xFFFFFFFFu) {
                    int bin = (int)(k >> 20);
                    q = (bin >= winlo && bin < winhi);
                }
            }
            ull mask = __ballot(q);
            if (mask) {
                int leader = __ffsll(mask) - 1;
                int pbase = 0;
                if (lane == leader) pbase = atomicAdd(&s_nsel, __popcll(mask));
                pbase = __shfl(pbase, leader);
                if (q) {
                    int pos = pbase + __popcll(mask & ((1ull << lane) - 1ull));
                    if (pos < CAP) s_skey[pos] = ((ull)k << 32) | (uint)e;
                }
            }
        }
        __syncthreads();
        int nsel = s_nsel; if (nsel > CAP) nsel = CAP;

        // bitonic sort CAP=512 ull keys ascending (pads last) -> exact total order
        for (int k2 = 2; k2 <= CAP; k2 <<= 1) {
            for (int j = k2 >> 1; j > 0; j >>= 1) {
                __syncthreads();
                if (t < CAP) {
                    int p = t ^ j;
                    if (p > t) {
                        ull a = s_skey[t], bb = s_skey[p];
                        bool up = ((t & k2) == 0);
                        if ((a > bb) == up) { s_skey[t] = bb; s_skey[p] = a; }
                    }
                }
            }
        }
        __syncthreads();

        // sorted walk on wave 0 (exact reference IoU + compare)
        if (t < 64) {
            int kept2 = s_kept;
            for (int cb = 0; cb < nsel && kept2 < MAXDET; cb += 64) {
                int ci = cb + lane;
                ull sk = (ci < nsel) ? s_skey[ci] : ~0ull;
                bool has = (sk != ~0ull);
                int idx = 0, lab = 0;
                float sc = 0.f, c0 = 0.f, c1 = 0.f, c2 = 0.f, c3 = 0.f, ca = 0.f;
                if (has) {
                    idx = (int)(sk & 0xFFFFFFFFull);
                    sc  = __uint_as_float(~(uint)(sk >> 32));
                    float4 rb = boxes[idx];
                    lab = labels[idx];
                    float lo = (float)lab * off;
                    c0 = rb.x + lo; c1 = rb.y + lo; c2 = rb.z + lo; c3 = rb.w + lo;
                    ca = (c2 - c0) * (c3 - c1);
                    for (int q = 0; q < kept2; ++q) {
                        float tlx = fmaxf(s_kbox[q][0], c0);
                        float tly = fmaxf(s_kbox[q][1], c1);
                        float brx = fminf(s_kbox[q][2], c2);
                        float bry = fminf(s_kbox[q][3], c3);
                        float ww = fmaxf(brx - tlx, 0.f);
                        float hh = fmaxf(bry - tly, 0.f);
                        float inter = ww * hh;
                        float iou = inter / (s_ka1[q] + ca - inter + 1e-6f);
                        if (iou > NMSTHR) { has = false; break; }
                    }
                }
                ull am = __ballot(has);
                while (am && kept2 < MAXDET) {
                    int f = __ffsll(am) - 1;
                    float f0 = __shfl(c0, f), f1 = __shfl(c1, f);
                    float f2 = __shfl(c2, f), f3 = __shfl(c3, f);
                    float fa = __shfl(ca, f);
                    int   fidx = __shfl(idx, f);
                    int   flab = __shfl(lab, f);
                    float fsc  = __shfl(sc, f);
                    if (lane == 0) {
                        s_kbox[kept2][0] = f0; s_kbox[kept2][1] = f1;
                        s_kbox[kept2][2] = f2; s_kbox[kept2][3] = f3;
                        s_ka1[kept2] = fa; s_kidx[kept2] = fidx;
                        s_kscr[kept2] = fsc; s_klab[kept2] = flab;
                    }
                    kept2++;
                    if (lane == f) has = false;
                    if (has) {
                        float tlx = fmaxf(f0, c0), tly = fmaxf(f1, c1);
                        float brx = fminf(f2, c2), bry = fminf(f3, c3);
                        float ww = fmaxf(brx - tlx, 0.f), hh = fmaxf(bry - tly, 0.f);
                        float inter = ww * hh;
                        float iou = inter / (fa + ca - inter + 1e-6f);
                        if (iou > NMSTHR) has = false;
                    }
                    am = __ballot(has);
                }
            }
            if (lane == 0) s_kept = kept2;
        }
        __syncthreads();
        if (t == 0) s_winlo = s_winhi;
    }
    __syncthreads();

    // ---- epilogue: boxes/scores/labels/valid (fp32) ----
    if (t < MAXDET) {
        int kept = s_kept;
        float4 obx = make_float4(0.f, 0.f, 0.f, 0.f);
        float osc = 0.f, olab = -1.f, oval = 0.f;
        if (t < kept) {
            int idx = s_kidx[t];
            obx  = boxes[idx];              // raw (non-offset) box
            osc  = s_kscr[t];
            olab = (float)s_klab[t];
            oval = 1.f;
        }
        float* ob = out + ((size_t)b * MAXDET + t) * 4;
        ob[0] = obx.x; ob[1] = obx.y; ob[2] = obx.z; ob[3] = obx.w;
        out[BATCH * MAXDET * 4 + b * MAXDET + t] = osc;
        out[BATCH * MAXDET * 5 + b * MAXDET + t] = olab;
        out[BATCH * MAXDET * 6 + b * MAXDET + t] = oval;
    }
}

extern "C" void kernel_launch(void* const* d_in, const int* in_sizes, int n_in,
                              void* d_out, int out_size, void* d_ws, size_t ws_size,
                              hipStream_t stream) {
    // setup_inputs() dict order: cls0, reg0, obj0, cls1, reg1, obj1, cls2, reg2, obj2
    const float* cls0 = (const float*)d_in[0];
    const float* reg0 = (const float*)d_in[1];
    const float* obj0 = (const float*)d_in[2];
    const float* cls1 = (const float*)d_in[3];
    const float* reg1 = (const float*)d_in[4];
    const float* obj1 = (const float*)d_in[5];
    const float* cls2 = (const float*)d_in[6];
    const float* reg2 = (const float*)d_in[7];
    const float* obj2 = (const float*)d_in[8];

    char* ws = (char*)d_ws;
    float4* wboxes  = (float4*)ws;
    float*  wscores = (float*)(ws + (size_t)BATCH * NA * sizeof(float4));
    int*    wlabels = (int*)(ws + (size_t)BATCH * NA * (sizeof(float4) + sizeof(float)));

    int total = BATCH * NA;   // 268800 = 1050 * 256 exactly
    decode_kernel<<<total / 256, 256, 0, stream>>>(
        cls0, reg0, obj0, cls1, reg1, obj1, cls2, reg2, obj2,
        wboxes, wscores, wlabels);

    nms_kernel<<<BATCH, NT, 0, stream>>>(wboxes, wscores, wlabels, (float*)d_out);
}